// Round 9
// baseline (226.621 us; speedup 1.0000x reference)
//
#include <hip/hip_runtime.h>
#include <cstdint>
#include <cstddef>

#define NUM_C 21
#define NROW 336      // 21 classes * 16 images, row r = cls*16 + img
#define N2   (NROW * NROW)
#define KSLABS 8      // k2: 2 K-halves x 4 waves -> 8 partial slabs

typedef __attribute__((ext_vector_type(8))) short short8;   // 8 bf16 = 4 VGPRs (MFMA A/B frag)
typedef __attribute__((ext_vector_type(4))) float f32x4;
typedef __attribute__((ext_vector_type(16))) float f32x16;  // 32x32 MFMA C/D frag
typedef __attribute__((ext_vector_type(4))) int int4v;

union frag_u { int4v i; short8 s; };
__device__ __forceinline__ short8 mk_frag(uint32_t a0, uint32_t a1, uint32_t a2, uint32_t a3) {
    frag_u u; u.i = int4v{(int)a0, (int)a1, (int)a2, (int)a3}; return u.s;
}
// packed bf16x2 one-hot: low16 = (eL==c), high16 = (eH==c), value 1.0bf16/0
__device__ __forceinline__ uint32_t mask_pair(uint32_t eL, uint32_t eH, uint32_t c) {
    return (eL == c ? 0x3F80u : 0u) | (eH == c ? 0x3F800000u : 0u);
}
// async global->LDS, 16B/lane (1KB/wave burst), aux=2 (nt). dst wave-uniform; HW writes
// dst + lane*16; the SOURCE address is per-lane (swizzle goes on the source - s09/m173).
__device__ __forceinline__ void load_lds16(const float* src, float* dst) {
    __builtin_amdgcn_global_load_lds((const __attribute__((address_space(1))) void*)src,
                                     (__attribute__((address_space(3))) void*)dst, 16, 0, 2);
}

// ---------------- K1: bilinear label resize (513x513 -> 64x64) + per-block histogram ----
__global__ __launch_bounds__(256) void k1_resize_hist(const int* __restrict__ labels,
                                                      uint8_t* __restrict__ lab,
                                                      int* __restrict__ countsPart,
                                                      float* __restrict__ out) {
    int b = blockIdx.x >> 4, strip = blockIdx.x & 15;
    if (blockIdx.x == 0 && threadIdx.x == 0) out[0] = 0.0f;  // K5 (later in stream) accumulates
    __shared__ int hist[NUM_C];
    if (threadIdx.x < NUM_C) hist[threadIdx.x] = 0;
    __syncthreads();

    int p = strip * 256 + threadIdx.x;      // pixel in [0,4096)
    int y = p >> 6, x = p & 63;
    const int* L = labels + (size_t)b * 263169;   // 513*513
    // sample_f = (i+0.5)*513/64 - 0.5 ; 513/64 = 8.015625 exact in fp32; range [3.5,508.5] -> no clamp
    float sy = (y + 0.5f) * 8.015625f - 0.5f;
    float sx = (x + 0.5f) * 8.015625f - 0.5f;
    int y0 = (int)sy; float fy = sy - (float)y0;
    int x0 = (int)sx; float fx = sx - (float)x0;
    const int* r0 = L + y0 * 513 + x0;
    float L00 = (float)__builtin_nontemporal_load(r0);
    float L01 = (float)__builtin_nontemporal_load(r0 + 1);
    float L10 = (float)__builtin_nontemporal_load(r0 + 513);
    float L11 = (float)__builtin_nontemporal_load(r0 + 514);
    float v0 = (1.0f - fx) * L00 + fx * L01;
    float v1 = (1.0f - fx) * L10 + fx * L11;
    float val = (1.0f - fy) * v0 + fy * v1;
    int c = (int)val;
    lab[b * 4096 + p] = (uint8_t)c;
    atomicAdd(&hist[c], 1);
    __syncthreads();
    if (threadIdx.x < NUM_C) countsPart[blockIdx.x * NUM_C + threadIdx.x] = hist[threadIdx.x];
}

// ---------------- K2: masked pooling, double-buffered LDS-staged 32x32x16 MFMA GEMM -----
// RESUBMISSION of round 8 (container infra failure, no HW data; source audited for hang
// hazards: uniform barriers, 64KB-exact LDS, bijective swizzle, closed dbuf race).
// Round-7 post-mortem: single-buffered stage->barrier->compute->barrier serialized the
// stream within each block (vmcnt(0) drain pays full HBM latency; 4 lockstepped blocks/CU
// don't interleave phases) -> k2 ~45us vs 21us floor. This version = the guide's minimum
// 2-phase template: issue next slab's global_load_lds BEFORE computing current, ONE
// barrier per slab; loads for slab t+1 stream during all of compute t + barrier wait.
// LDS capacity trick: padded dbuf (2x32x260f = 66.5KB) exceeds the 64KB/WG limit, and
// unpadded stride-256 is a 32-way conflict. So keep LDS LINEAR [2][32][256] = 65536B
// exactly, and bake a 16B-slot XOR swizzle into the per-lane GLOBAL source address
// (legal: gload_lds src is per-lane, dst stays uniform+linear). Row r slot s holds global
// slot s^r; reads use slot (sA^r) -> each bank-quad hit exactly 4x per ds_read_b128 (the
// b128 minimum = conflict-free); each stage instr still reads one permuted-but-coalesced
// 1KB block (1 instr/row).
// Grid 512 = b(16) x dg(16) x ks(2): 2 blocks/CU exactly (128KB LDS), ~64KB loads in
// flight per CU (>= ~23KB BW*latency product) -> stream-bound.
// Layouts (verified r5-r7, absmax 0.0): A row = lane&31 (=class, >=21 auto-zero),
// B col = lane&31 (=d), k = g*8+j; C/D col = lane&31, row = (j&3)+8*(j>>2)+4*g.
// fp32 -> bf16 hi + exact-residual lo, fp32 accumulate.
__global__ __launch_bounds__(256) void k2_sums(const float* __restrict__ feat,
                                               const uint8_t* __restrict__ lab,
                                               float* __restrict__ sums_part) {
    int bid = blockIdx.x;                 // 512 = b(16) x dg(16) x ks(2)
    int b = bid >> 5, dg = (bid >> 1) & 15, ks = bid & 1;
    int t = threadIdx.x, wv = t >> 6, lane = t & 63;
    int g = lane >> 5;                    // k-group (0,1)
    int r = lane & 31;                    // d-row for reads / class for A
    uint32_t c = lane & 31;
    __shared__ float tile[2][32][256];    // 65536 B exactly; swizzled via source perm

    const float* fbase = feat + ((size_t)(b * 512 + dg * 32)) * 4096 + ks * 2048;
    const uint8_t* lbase = lab + b * 4096 + ks * 2048;

    f32x16 acc;
#pragma unroll
    for (int j = 0; j < 16; ++j) acc[j] = 0.0f;

    // stage slab (256 px) into buffer bb: wave wv stages rows wv*8..wv*8+7, one 1KB
    // burst each; lane supplies global slot (lane ^ row) -> LDS slot lane (linear dst).
#define STAGE(bb, slab)                                                              \
    {                                                                                \
        int px0 = (slab) * 256;                                                      \
        _Pragma("unroll")                                                            \
        for (int rr = 0; rr < 8; ++rr) {                                             \
            int row = wv * 8 + rr;                                                   \
            load_lds16(fbase + (size_t)row * 4096 + px0 + ((lane ^ row) << 2),       \
                       &tile[bb][row][0]);                                           \
        }                                                                            \
    }

    STAGE(0, 0)
    __syncthreads();
    int buf = 0;

    for (int slab = 0; slab < 8; ++slab) {
        if (slab < 7) STAGE(buf ^ 1, slab + 1)   // async; streams during compute below

        const uint8_t* lp = lbase + slab * 256 + wv * 64 + g * 8;
        const float* trow = &tile[buf][r][0];
#pragma unroll
        for (int ch = 0; ch < 4; ++ch) {
            int sA = wv * 16 + ch * 4 + g * 2;            // 16B-slot index of fA
            f32x4 fA = *(const f32x4*)(trow + ((sA ^ r) << 2));
            f32x4 fB = *(const f32x4*)(trow + (((sA + 1) ^ r) << 2));
            uint2 wl = *(const uint2*)(lp + ch * 16);     // labels: cached, uniform per g

            uint32_t u0 = __float_as_uint(fA[0]), u1 = __float_as_uint(fA[1]),
                     u2 = __float_as_uint(fA[2]), u3 = __float_as_uint(fA[3]),
                     u4 = __float_as_uint(fB[0]), u5 = __float_as_uint(fB[1]),
                     u6 = __float_as_uint(fB[2]), u7 = __float_as_uint(fB[3]);
            // hi = truncate-to-bf16: pack high16 of consecutive floats (1 v_perm/pair)
            short8 bHi = mk_frag(__builtin_amdgcn_perm(u1, u0, 0x07060302u),
                                 __builtin_amdgcn_perm(u3, u2, 0x07060302u),
                                 __builtin_amdgcn_perm(u5, u4, 0x07060302u),
                                 __builtin_amdgcn_perm(u7, u6, 0x07060302u));
            // lo = truncate-to-bf16 of exact residual f - hi (shared exponent -> exact)
            float t0 = fA[0] - __uint_as_float(u0 & 0xFFFF0000u);
            float t1 = fA[1] - __uint_as_float(u1 & 0xFFFF0000u);
            float t2 = fA[2] - __uint_as_float(u2 & 0xFFFF0000u);
            float t3 = fA[3] - __uint_as_float(u3 & 0xFFFF0000u);
            float t4 = fB[0] - __uint_as_float(u4 & 0xFFFF0000u);
            float t5 = fB[1] - __uint_as_float(u5 & 0xFFFF0000u);
            float t6 = fB[2] - __uint_as_float(u6 & 0xFFFF0000u);
            float t7 = fB[3] - __uint_as_float(u7 & 0xFFFF0000u);
            short8 bLo = mk_frag(
                __builtin_amdgcn_perm(__float_as_uint(t1), __float_as_uint(t0), 0x07060302u),
                __builtin_amdgcn_perm(__float_as_uint(t3), __float_as_uint(t2), 0x07060302u),
                __builtin_amdgcn_perm(__float_as_uint(t5), __float_as_uint(t4), 0x07060302u),
                __builtin_amdgcn_perm(__float_as_uint(t7), __float_as_uint(t6), 0x07060302u));

            uint32_t e0 = wl.x & 255u, e1 = (wl.x >> 8) & 255u,
                     e2 = (wl.x >> 16) & 255u, e3 = wl.x >> 24;
            uint32_t e4 = wl.y & 255u, e5 = (wl.y >> 8) & 255u,
                     e6 = (wl.y >> 16) & 255u, e7 = wl.y >> 24;
            short8 a = mk_frag(mask_pair(e0, e1, c), mask_pair(e2, e3, c),
                               mask_pair(e4, e5, c), mask_pair(e6, e7, c));

            acc = __builtin_amdgcn_mfma_f32_32x32x16_bf16(a, bHi, acc, 0, 0, 0);
            acc = __builtin_amdgcn_mfma_f32_32x32x16_bf16(a, bLo, acc, 0, 0, 0);
        }
        __syncthreads();   // drains next slab's stage; protects buf before overwrite
        buf ^= 1;
    }
#undef STAGE

    // C/D: col = lane&31 (=d), row = (j&3) + 8*(j>>2) + 4*g (=class).
    // Per (j): 32 lanes write 128B consecutive -> coalesced.
    float* sp = sums_part + (size_t)(ks * 4 + wv) * NROW * 512;
    int d = dg * 32 + (lane & 31);
    int rb = 4 * g;
#pragma unroll
    for (int j = 0; j < 16; ++j) {
        int row = (j & 3) + 8 * (j >> 2) + rb;
        if (row < NUM_C) sp[(size_t)(row * 16 + b) * 512 + d] = acc[j];
    }
}

// ---------------- K3: fold 8 partial slabs -> sums[336][512] ----------------------------
// Reads its own just-written 5.5MB (L2/L3-warm): keep cached loads.
__global__ __launch_bounds__(256) void k3_fold(const float4* __restrict__ part,
                                               float4* __restrict__ sums) {
    int idx = blockIdx.x * 256 + threadIdx.x;   // 43008 float4s = 336*512 floats
    float4 s = part[idx];
#pragma unroll
    for (int q = 1; q < KSLABS; ++q) {
        float4 v = part[q * 43008 + idx];
        s.x += v.x; s.y += v.y; s.z += v.z; s.w += v.w;
    }
    sums[idx] = s;
}

// ---------------- K4: Gram of folded sums, k-split into 8 partial slabs -----------------
__global__ __launch_bounds__(64) void k4_gram(const float* __restrict__ sums,
                                              float* __restrict__ gpart) {
    int row0 = blockIdx.x * 32, col0 = blockIdx.y * 32, k0 = blockIdx.z * 64;
    __shared__ float A[32 * 66], Bt[32 * 66];
    int t = threadIdx.x;
    int row = t >> 1, kk0 = (t & 1) * 32;
#pragma unroll
    for (int q = 0; q < 8; ++q) {
        int kk = kk0 + q * 4;
        int ra = row0 + row, rb = col0 + row;
        float4 va = (ra < NROW) ? *(const float4*)&sums[(size_t)ra * 512 + k0 + kk]
                                : make_float4(0.f, 0.f, 0.f, 0.f);
        float4 vb = (rb < NROW) ? *(const float4*)&sums[(size_t)rb * 512 + k0 + kk]
                                : make_float4(0.f, 0.f, 0.f, 0.f);
        *(float2*)&A[row * 66 + kk]      = make_float2(va.x, va.y);
        *(float2*)&A[row * 66 + kk + 2]  = make_float2(va.z, va.w);
        *(float2*)&Bt[row * 66 + kk]     = make_float2(vb.x, vb.y);
        *(float2*)&Bt[row * 66 + kk + 2] = make_float2(vb.z, vb.w);
    }
    __syncthreads();
    int ty = t >> 3, tx = t & 7;
    float acc[4][4] = {};
    for (int kk = 0; kk < 64; kk += 2) {
        float2 a[4], bb[4];
#pragma unroll
        for (int u = 0; u < 4; ++u) {
            a[u]  = *(const float2*)&A[(ty * 4 + u) * 66 + kk];
            bb[u] = *(const float2*)&Bt[(tx * 4 + u) * 66 + kk];
        }
#pragma unroll
        for (int u = 0; u < 4; ++u)
#pragma unroll
            for (int v = 0; v < 4; ++v)
                acc[u][v] += a[u].x * bb[v].x + a[u].y * bb[v].y;
    }
    float* gp = gpart + (size_t)blockIdx.z * N2;
#pragma unroll
    for (int u = 0; u < 4; ++u) {
        int r1 = row0 + ty * 4 + u;
        if (r1 >= NROW) continue;
        int r2 = col0 + tx * 4;
        if (r2 + 3 < NROW) {
            *(float4*)&gp[(size_t)r1 * NROW + r2] =
                make_float4(acc[u][0], acc[u][1], acc[u][2], acc[u][3]);
        } else {
#pragma unroll
            for (int v = 0; v < 4; ++v)
                if (r2 + v < NROW) gp[(size_t)r1 * NROW + r2 + v] = acc[u][v];
        }
    }
}

// ---------------- K5: per-class masked LSE loss, single pass ----------------------------
__global__ __launch_bounds__(1024) void k5_loss(const float* __restrict__ gpart,
                                                const int* __restrict__ countsPart,
                                                float* __restrict__ out) {
    int c = blockIdx.x, t = threadIdx.x;
    int wv = t >> 6, lane = t & 63;
    __shared__ float invnL[NROW];
    __shared__ uint8_t presL[NROW];
    __shared__ float redE[16], redD[16], redL[16];

    for (int r = t; r < NROW; r += 1024) {
        float ss = 0.0f;
#pragma unroll
        for (int s = 0; s < 8; ++s) ss += gpart[(size_t)s * N2 + (size_t)r * 337];
        invnL[r] = 1.0f / fmaxf(sqrtf(ss), 1e-12f);
        int img = r & 15, cls = r >> 4;
        int cnt = 0;
#pragma unroll
        for (int s = 0; s < 16; ++s) cnt += countsPart[(img * 16 + s) * NUM_C + cls];
        presL[r] = cnt > 0 ? 1 : 0;
    }
    __syncthreads();

    int nc = 0;
#pragma unroll
    for (int j = 0; j < 16; ++j) nc += presL[c * 16 + j];
    if (nc == 0) return;   // class absent in all images: contributes 0 (uniform exit)

    float eS = 0.0f, dE = 0.0f, dL = 0.0f;
    for (int idx = t; idx < 16 * NROW; idx += 1024) {
        int i = idx / NROW, r2 = idx - i * NROW;
        int r1 = c * 16 + i;
        float g = 0.0f;
#pragma unroll
        for (int s = 0; s < 8; ++s) g += gpart[(size_t)s * N2 + (size_t)r1 * NROW + r2];
        if (presL[r1] && presL[r2]) {
            float sv = g * invnL[r1] * invnL[r2] * 10.0f;   // /T, T=0.1
            float e = expf(sv - 10.0f);
            eS += e;
            if ((r2 >> 4) == c) { dE += e; dL += sv; }      // diag block (appears twice)
        }
    }
#pragma unroll
    for (int off = 32; off >= 1; off >>= 1) {
        eS += __shfl_xor(eS, off, 64);
        dE += __shfl_xor(dE, off, 64);
        dL += __shfl_xor(dL, off, 64);
    }
    if (lane == 0) { redE[wv] = eS; redD[wv] = dE; redL[wv] = dL; }
    __syncthreads();
    if (t == 0) {
        float E = 0, D = 0, Ln = 0;
#pragma unroll
        for (int w = 0; w < 16; ++w) { E += redE[w]; D += redD[w]; Ln += redL[w]; }
        float lse = 10.0f + logf(E + D);
        float posMean = Ln / (float)(nc * nc);
        atomicAdd(out, lse - posMean);
    }
}

// ---------------- launcher --------------------------------------------------------------
extern "C" void kernel_launch(void* const* d_in, const int* in_sizes, int n_in,
                              void* d_out, int out_size, void* d_ws, size_t ws_size,
                              hipStream_t stream) {
    const float* features = (const float*)d_in[0];
    const int* labels = (const int*)d_in[1];
    char* ws = (char*)d_ws;

    uint8_t* lab     = (uint8_t*)ws;                              // 65536 B
    int* countsPart  = (int*)(ws + 65536);                        // 21504 B
    float* sums_part = (float*)(ws + 87040);                      // 8*336*512*4 = 5505024 B
    float* sums      = (float*)(ws + 87040 + 5505024);            // 688128 B
    float* gpart     = (float*)(ws + 87040 + 5505024 + 688128);   // 3612672 B
    float* out       = (float*)d_out;

    k1_resize_hist<<<256, 256, 0, stream>>>(labels, lab, countsPart, out);
    k2_sums<<<512, 256, 0, stream>>>(features, lab, sums_part);
    k3_fold<<<168, 256, 0, stream>>>((const float4*)sums_part, (float4*)sums);
    k4_gram<<<dim3(11, 11, 8), 64, 0, stream>>>(sums, gpart);
    k5_loss<<<21, 1024, 0, stream>>>(gpart, countsPart, out);
}

// Round 10
// 217.846 us; speedup vs baseline: 1.0403x; 1.0403x over previous
//
#include <hip/hip_runtime.h>
#include <cstdint>
#include <cstddef>

#define NUM_C 21
#define NROW 336      // 21 classes * 16 images, row r = cls*16 + img
#define N2   (NROW * NROW)
#define KSLABS 32     // k2: 8 K-ranges x 4 waves -> 32 partial slabs

typedef __attribute__((ext_vector_type(8))) short short8;   // 8 bf16 = 4 VGPRs (MFMA A/B frag)
typedef __attribute__((ext_vector_type(4))) float f32x4;
typedef __attribute__((ext_vector_type(16))) float f32x16;  // 32x32 MFMA C/D frag
typedef __attribute__((ext_vector_type(4))) int int4v;

union frag_u { int4v i; short8 s; };
__device__ __forceinline__ short8 mk_frag(uint32_t a0, uint32_t a1, uint32_t a2, uint32_t a3) {
    frag_u u; u.i = int4v{(int)a0, (int)a1, (int)a2, (int)a3}; return u.s;
}
// packed bf16x2 one-hot: low16 = (eL==c), high16 = (eH==c), value 1.0bf16/0
__device__ __forceinline__ uint32_t mask_pair(uint32_t eL, uint32_t eH, uint32_t c) {
    return (eL == c ? 0x3F80u : 0u) | (eH == c ? 0x3F800000u : 0u);
}
// async global->LDS, 16B/lane (1KB/wave burst), aux=2 (nt). dst wave-uniform; HW writes
// dst + lane*16; the SOURCE address is per-lane (swizzle goes on the source - s09/m173).
__device__ __forceinline__ void load_lds16(const float* src, float* dst) {
    __builtin_amdgcn_global_load_lds((const __attribute__((address_space(1))) void*)src,
                                     (__attribute__((address_space(3))) void*)dst, 16, 0, 2);
}

// ---------------- K1: bilinear label resize (513x513 -> 64x64) + per-block histogram ----
__global__ __launch_bounds__(256) void k1_resize_hist(const int* __restrict__ labels,
                                                      uint8_t* __restrict__ lab,
                                                      int* __restrict__ countsPart,
                                                      float* __restrict__ out) {
    int b = blockIdx.x >> 4, strip = blockIdx.x & 15;
    if (blockIdx.x == 0 && threadIdx.x == 0) out[0] = 0.0f;  // K5 (later in stream) accumulates
    __shared__ int hist[NUM_C];
    if (threadIdx.x < NUM_C) hist[threadIdx.x] = 0;
    __syncthreads();

    int p = strip * 256 + threadIdx.x;      // pixel in [0,4096)
    int y = p >> 6, x = p & 63;
    const int* L = labels + (size_t)b * 263169;   // 513*513
    // sample_f = (i+0.5)*513/64 - 0.5 ; 513/64 = 8.015625 exact in fp32; range [3.5,508.5] -> no clamp
    float sy = (y + 0.5f) * 8.015625f - 0.5f;
    float sx = (x + 0.5f) * 8.015625f - 0.5f;
    int y0 = (int)sy; float fy = sy - (float)y0;
    int x0 = (int)sx; float fx = sx - (float)x0;
    const int* r0 = L + y0 * 513 + x0;
    float L00 = (float)__builtin_nontemporal_load(r0);
    float L01 = (float)__builtin_nontemporal_load(r0 + 1);
    float L10 = (float)__builtin_nontemporal_load(r0 + 513);
    float L11 = (float)__builtin_nontemporal_load(r0 + 514);
    float v0 = (1.0f - fx) * L00 + fx * L01;
    float v1 = (1.0f - fx) * L10 + fx * L11;
    float val = (1.0f - fy) * v0 + fy * v1;
    int c = (int)val;
    lab[b * 4096 + p] = (uint8_t)c;
    atomicAdd(&hist[c], 1);
    __syncthreads();
    if (threadIdx.x < NUM_C) countsPart[blockIdx.x * NUM_C + threadIdx.x] = hist[threadIdx.x];
}

// ---------------- K2: masked pooling, single-buffer LDS-staged 32x32x16 MFMA, 8 blk/CU --
// Round-9 post-mortem: dbuf regressed (226.6 vs r7 217.7) -- __syncthreads drains
// vmcnt(0) INCLUDING the prefetched next-slab loads, so the 2-phase overlap bought only
// the short compute phase while halving residency 4->2 blocks/CU. Block-level TLP is the
// effective pipeline here. This round maximizes it: tile [32][128] fp32 = 16KB exact ->
// 8 blocks/CU (128KB LDS, 2048 thr/CU -- both caps), grid 2048 = b16 x dg16 x ks8.
// Discriminating experiment: if k2 is still latency/TLP-short, this doubles r7's overlap
// -> k2 ~26-32us. If k2 stays ~45us, the ~3TB/s read-path ceiling is confirmed and r7
// was already at roofline.
// Staging: one gload_lds instr = 1KB = rows {2m, 2m+1} (512B each); per-lane SOURCE
// carries the XOR swizzle (slot s of row r holds global slot s^r); reads use slot sA^r
// -> 4 lanes per bank-quad on ds_read_b128 (minimum). aux=2 nt (r4 win).
// Layouts (verified r5-r9, absmax 0.0): A row = lane&31 (=class, >=21 auto-zero),
// B col = lane&31 (=d), k = g*8+j; C/D col = lane&31, row = (j&3)+8*(j>>2)+4*g.
// fp32 -> bf16 hi + exact-residual lo, fp32 accumulate.
__global__ __launch_bounds__(256) void k2_sums(const float* __restrict__ feat,
                                               const uint8_t* __restrict__ lab,
                                               float* __restrict__ sums_part) {
    int bid = blockIdx.x;                 // 2048 = b(16) x dg(16) x ks(8)
    int b = bid >> 7, dg = (bid >> 3) & 15, ks = bid & 7;
    int t = threadIdx.x, wv = t >> 6, lane = t & 63;
    int g = lane >> 5;                    // k-group (0,1)
    int r = lane & 31;                    // d-row for reads / class for A
    uint32_t c = lane & 31;
    __shared__ float tile[32][128];       // 16384 B exact; swizzled via source perm

    const float* fbase = feat + ((size_t)(b * 512 + dg * 32)) * 4096 + ks * 512;
    const uint8_t* lbase = lab + b * 4096 + ks * 512;

    f32x16 acc;
#pragma unroll
    for (int j = 0; j < 16; ++j) acc[j] = 0.0f;

    int srow = (lane >> 5);               // stage: which of the 2 rows this lane covers
    int sslot = lane & 31;                // stage: 16B slot within the row

    for (int slab = 0; slab < 4; ++slab) {
        int px0 = slab * 128;
        // stage 16KB: wave wv covers row-pairs m = wv*4..wv*4+3 (rows 8wv..8wv+7),
        // one 1KB burst per pair; source slot = sslot ^ row (bijective 5-bit XOR).
#pragma unroll
        for (int m = 0; m < 4; ++m) {
            int row = (wv * 4 + m) * 2 + srow;
            load_lds16(fbase + (size_t)row * 4096 + px0 + ((sslot ^ row) << 2),
                       &tile[wv * 8 + m * 2][0]);
        }
        __syncthreads();   // vmcnt(0) drain; 8 blocks/CU interleave these stalls

        // compute: wave's K-share = px [px0 + wv*32, +32) = slots [wv*8, wv*8+8)
        const uint8_t* lp = lbase + px0 + wv * 32 + g * 8;
#pragma unroll
        for (int ch = 0; ch < 2; ++ch) {
            int sA = wv * 8 + ch * 4 + g * 2;             // 16B-slot index of fA (even)
            f32x4 fA = *(const f32x4*)(&tile[r][0] + ((sA ^ r) << 2));
            f32x4 fB = *(const f32x4*)(&tile[r][0] + (((sA + 1) ^ r) << 2));
            uint2 wl = *(const uint2*)(lp + ch * 16);     // labels: cached, uniform per g

            uint32_t u0 = __float_as_uint(fA[0]), u1 = __float_as_uint(fA[1]),
                     u2 = __float_as_uint(fA[2]), u3 = __float_as_uint(fA[3]),
                     u4 = __float_as_uint(fB[0]), u5 = __float_as_uint(fB[1]),
                     u6 = __float_as_uint(fB[2]), u7 = __float_as_uint(fB[3]);
            // hi = truncate-to-bf16: pack high16 of consecutive floats (1 v_perm/pair)
            short8 bHi = mk_frag(__builtin_amdgcn_perm(u1, u0, 0x07060302u),
                                 __builtin_amdgcn_perm(u3, u2, 0x07060302u),
                                 __builtin_amdgcn_perm(u5, u4, 0x07060302u),
                                 __builtin_amdgcn_perm(u7, u6, 0x07060302u));
            // lo = truncate-to-bf16 of exact residual f - hi (shared exponent -> exact)
            float t0 = fA[0] - __uint_as_float(u0 & 0xFFFF0000u);
            float t1 = fA[1] - __uint_as_float(u1 & 0xFFFF0000u);
            float t2 = fA[2] - __uint_as_float(u2 & 0xFFFF0000u);
            float t3 = fA[3] - __uint_as_float(u3 & 0xFFFF0000u);
            float t4 = fB[0] - __uint_as_float(u4 & 0xFFFF0000u);
            float t5 = fB[1] - __uint_as_float(u5 & 0xFFFF0000u);
            float t6 = fB[2] - __uint_as_float(u6 & 0xFFFF0000u);
            float t7 = fB[3] - __uint_as_float(u7 & 0xFFFF0000u);
            short8 bLo = mk_frag(
                __builtin_amdgcn_perm(__float_as_uint(t1), __float_as_uint(t0), 0x07060302u),
                __builtin_amdgcn_perm(__float_as_uint(t3), __float_as_uint(t2), 0x07060302u),
                __builtin_amdgcn_perm(__float_as_uint(t5), __float_as_uint(t4), 0x07060302u),
                __builtin_amdgcn_perm(__float_as_uint(t7), __float_as_uint(t6), 0x07060302u));

            uint32_t e0 = wl.x & 255u, e1 = (wl.x >> 8) & 255u,
                     e2 = (wl.x >> 16) & 255u, e3 = wl.x >> 24;
            uint32_t e4 = wl.y & 255u, e5 = (wl.y >> 8) & 255u,
                     e6 = (wl.y >> 16) & 255u, e7 = wl.y >> 24;
            short8 a = mk_frag(mask_pair(e0, e1, c), mask_pair(e2, e3, c),
                               mask_pair(e4, e5, c), mask_pair(e6, e7, c));

            acc = __builtin_amdgcn_mfma_f32_32x32x16_bf16(a, bHi, acc, 0, 0, 0);
            acc = __builtin_amdgcn_mfma_f32_32x32x16_bf16(a, bLo, acc, 0, 0, 0);
        }
        __syncthreads();   // protect tile before next slab overwrites
    }

    // C/D: col = lane&31 (=d), row = (j&3) + 8*(j>>2) + 4*g (=class).
    // Per (j): 32 lanes write 128B consecutive -> coalesced.
    float* sp = sums_part + (size_t)(ks * 4 + wv) * NROW * 512;
    int d = dg * 32 + (lane & 31);
    int rb = 4 * g;
#pragma unroll
    for (int j = 0; j < 16; ++j) {
        int row = (j & 3) + 8 * (j >> 2) + rb;
        if (row < NUM_C) sp[(size_t)(row * 16 + b) * 512 + d] = acc[j];
    }
}

// ---------------- K3: fold 32 partial slabs -> sums[336][512] ---------------------------
// Reads its own just-written 22MB (L2/L3-warm): keep cached loads. Two-level sum to
// limit loads-in-flight per thread.
__global__ __launch_bounds__(256) void k3_fold(const float4* __restrict__ part,
                                               float4* __restrict__ sums) {
    int idx = blockIdx.x * 256 + threadIdx.x;   // 43008 float4s = 336*512 floats
    float4 s = make_float4(0.f, 0.f, 0.f, 0.f);
#pragma unroll 8
    for (int q = 0; q < KSLABS; ++q) {
        float4 v = part[q * 43008 + idx];
        s.x += v.x; s.y += v.y; s.z += v.z; s.w += v.w;
    }
    sums[idx] = s;
}

// ---------------- K4: Gram of folded sums, k-split into 8 partial slabs -----------------
__global__ __launch_bounds__(64) void k4_gram(const float* __restrict__ sums,
                                              float* __restrict__ gpart) {
    int row0 = blockIdx.x * 32, col0 = blockIdx.y * 32, k0 = blockIdx.z * 64;
    __shared__ float A[32 * 66], Bt[32 * 66];
    int t = threadIdx.x;
    int row = t >> 1, kk0 = (t & 1) * 32;
#pragma unroll
    for (int q = 0; q < 8; ++q) {
        int kk = kk0 + q * 4;
        int ra = row0 + row, rb = col0 + row;
        float4 va = (ra < NROW) ? *(const float4*)&sums[(size_t)ra * 512 + k0 + kk]
                                : make_float4(0.f, 0.f, 0.f, 0.f);
        float4 vb = (rb < NROW) ? *(const float4*)&sums[(size_t)rb * 512 + k0 + kk]
                                : make_float4(0.f, 0.f, 0.f, 0.f);
        *(float2*)&A[row * 66 + kk]      = make_float2(va.x, va.y);
        *(float2*)&A[row * 66 + kk + 2]  = make_float2(va.z, va.w);
        *(float2*)&Bt[row * 66 + kk]     = make_float2(vb.x, vb.y);
        *(float2*)&Bt[row * 66 + kk + 2] = make_float2(vb.z, vb.w);
    }
    __syncthreads();
    int ty = t >> 3, tx = t & 7;
    float acc[4][4] = {};
    for (int kk = 0; kk < 64; kk += 2) {
        float2 a[4], bb[4];
#pragma unroll
        for (int u = 0; u < 4; ++u) {
            a[u]  = *(const float2*)&A[(ty * 4 + u) * 66 + kk];
            bb[u] = *(const float2*)&Bt[(tx * 4 + u) * 66 + kk];
        }
#pragma unroll
        for (int u = 0; u < 4; ++u)
#pragma unroll
            for (int v = 0; v < 4; ++v)
                acc[u][v] += a[u].x * bb[v].x + a[u].y * bb[v].y;
    }
    float* gp = gpart + (size_t)blockIdx.z * N2;
#pragma unroll
    for (int u = 0; u < 4; ++u) {
        int r1 = row0 + ty * 4 + u;
        if (r1 >= NROW) continue;
        int r2 = col0 + tx * 4;
        if (r2 + 3 < NROW) {
            *(float4*)&gp[(size_t)r1 * NROW + r2] =
                make_float4(acc[u][0], acc[u][1], acc[u][2], acc[u][3]);
        } else {
#pragma unroll
            for (int v = 0; v < 4; ++v)
                if (r2 + v < NROW) gp[(size_t)r1 * NROW + r2 + v] = acc[u][v];
        }
    }
}

// ---------------- K5: per-class masked LSE loss, single pass ----------------------------
__global__ __launch_bounds__(1024) void k5_loss(const float* __restrict__ gpart,
                                                const int* __restrict__ countsPart,
                                                float* __restrict__ out) {
    int c = blockIdx.x, t = threadIdx.x;
    int wv = t >> 6, lane = t & 63;
    __shared__ float invnL[NROW];
    __shared__ uint8_t presL[NROW];
    __shared__ float redE[16], redD[16], redL[16];

    for (int r = t; r < NROW; r += 1024) {
        float ss = 0.0f;
#pragma unroll
        for (int s = 0; s < 8; ++s) ss += gpart[(size_t)s * N2 + (size_t)r * 337];
        invnL[r] = 1.0f / fmaxf(sqrtf(ss), 1e-12f);
        int img = r & 15, cls = r >> 4;
        int cnt = 0;
#pragma unroll
        for (int s = 0; s < 16; ++s) cnt += countsPart[(img * 16 + s) * NUM_C + cls];
        presL[r] = cnt > 0 ? 1 : 0;
    }
    __syncthreads();

    int nc = 0;
#pragma unroll
    for (int j = 0; j < 16; ++j) nc += presL[c * 16 + j];
    if (nc == 0) return;   // class absent in all images: contributes 0 (uniform exit)

    float eS = 0.0f, dE = 0.0f, dL = 0.0f;
    for (int idx = t; idx < 16 * NROW; idx += 1024) {
        int i = idx / NROW, r2 = idx - i * NROW;
        int r1 = c * 16 + i;
        float g = 0.0f;
#pragma unroll
        for (int s = 0; s < 8; ++s) g += gpart[(size_t)s * N2 + (size_t)r1 * NROW + r2];
        if (presL[r1] && presL[r2]) {
            float sv = g * invnL[r1] * invnL[r2] * 10.0f;   // /T, T=0.1
            float e = expf(sv - 10.0f);
            eS += e;
            if ((r2 >> 4) == c) { dE += e; dL += sv; }      // diag block (appears twice)
        }
    }
#pragma unroll
    for (int off = 32; off >= 1; off >>= 1) {
        eS += __shfl_xor(eS, off, 64);
        dE += __shfl_xor(dE, off, 64);
        dL += __shfl_xor(dL, off, 64);
    }
    if (lane == 0) { redE[wv] = eS; redD[wv] = dE; redL[wv] = dL; }
    __syncthreads();
    if (t == 0) {
        float E = 0, D = 0, Ln = 0;
#pragma unroll
        for (int w = 0; w < 16; ++w) { E += redE[w]; D += redD[w]; Ln += redL[w]; }
        float lse = 10.0f + logf(E + D);
        float posMean = Ln / (float)(nc * nc);
        atomicAdd(out, lse - posMean);
    }
}

// ---------------- launcher --------------------------------------------------------------
extern "C" void kernel_launch(void* const* d_in, const int* in_sizes, int n_in,
                              void* d_out, int out_size, void* d_ws, size_t ws_size,
                              hipStream_t stream) {
    const float* features = (const float*)d_in[0];
    const int* labels = (const int*)d_in[1];
    char* ws = (char*)d_ws;

    uint8_t* lab     = (uint8_t*)ws;                               // 65536 B
    int* countsPart  = (int*)(ws + 65536);                         // 21504 B
    float* sums_part = (float*)(ws + 87040);                       // 32*336*512*4 = 22020096 B
    float* sums      = (float*)(ws + 87040 + 22020096);            // 688128 B
    float* gpart     = (float*)(ws + 87040 + 22020096 + 688128);   // 3612672 B
    float* out       = (float*)d_out;

    k1_resize_hist<<<256, 256, 0, stream>>>(labels, lab, countsPart, out);
    k2_sums<<<2048, 256, 0, stream>>>(features, lab, sums_part);
    k3_fold<<<168, 256, 0, stream>>>((const float4*)sums_part, (float4*)sums);
    k4_gram<<<dim3(11, 11, 8), 64, 0, stream>>>(sums, gpart);
    k5_loss<<<21, 1024, 0, stream>>>(gpart, countsPart, out);
}